// Round 3
// baseline (18304.956 us; speedup 1.0000x reference)
//
#include <hip/hip_runtime.h>

#define N_ 2048
#define T_ 512
#define B_ 32
#define NWG 64            // workgroups; each owns 32 neurons; 64 blocks <= 256 CUs -> all co-resident
#define NS 32
#define DT_ 1e-4f
#define U_CONST_ 0.3f
#define TAU_F_ 1.5f
#define TAU_D_ 0.3f
#define ALPHA_ 1.5f
#define I_B_ 8.0f
#define J_EI_ 1.1f
#define J_IE_ 2.2f
#define INV_TAU 125.0f          // 1/0.008
#define INV_ALPHA (1.0f/1.5f)
#define LO_SCALE 4096.0f        // 2^12: keeps lo parts out of fp16 denormal range
#define INV_LO_SCALE 2.44140625e-4f

// d_out float offsets: all_h, all_u, all_x, all_hI, outputs
#define U_OFF  (512ull*32*2048)
#define X_OFF  (2ull*512*32*2048)
#define HI_OFF (3ull*512*32*2048)
#define OUT_OFF (HI_OFF + 512ull*32)

typedef _Float16 half8 __attribute__((ext_vector_type(8)));
typedef float f32x4 __attribute__((ext_vector_type(4)));

// persistent-kernel scratch: written before read every step of every launch,
// so poison/stale state is harmless. Kept out of d_ws to avoid ws_size limits.
__device__ _Float16 g_vh[2 * B_ * N_];
__device__ _Float16 g_vl[2 * B_ * N_];
__device__ float    g_rp[2 * NWG * B_];

__device__ inline float rate_f(float h) {
  // ALPHA * softplus(h/ALPHA) == ALPHA * (max(z,0) + log1p(exp(-|z|)))
  float z = h * INV_ALPHA;
  return ALPHA_ * (fmaxf(z, 0.0f) + log1pf(expf(-fabsf(z))));
}

__global__ void init_kernel(unsigned* __restrict__ bar) {
  if (threadIdx.x == 0) *bar = 0u;
}

__global__ __launch_bounds__(256, 1) void stp_kernel(
    const float* __restrict__ inp, const float* __restrict__ W_in,
    const float* __restrict__ J, float* __restrict__ out,
    unsigned* __restrict__ bar)
{
  const int tid  = threadIdx.x;
  const int wg   = blockIdx.x;
  const int wave = tid >> 6;
  const int lane = tid & 63;

  __shared__ float sh_h[1024], sh_u[1024], sh_x[1024];
  __shared__ float sh_C[4][1024];
  __shared__ float sh_hI[32], sh_RI[32], sh_rsum[32], sh_inp[32];

  // ---- load this wave's J slice into registers as split fp16 B-fragments ----
  // jh/jl[nt][c] hold J[wg*32 + nt*16 + (lane&15)][wave*512 + c*32 + (lane>>4)*8 + j]
  // J = jh + jl * 2^-12 (lo pre-scaled by 2^12)
  half8 jh[2][16], jl[2][16];
  {
    const int r = lane & 15, q = lane >> 4;
    #pragma unroll
    for (int nt = 0; nt < 2; ++nt)
      #pragma unroll
      for (int c = 0; c < 16; ++c) {
        const float* src = J + (size_t)(wg*NS + nt*16 + r) * N_ + wave*512 + c*32 + q*8;
        half8 hv, lv;
        #pragma unroll
        for (int j = 0; j < 8; ++j) {
          float f = src[j];
          _Float16 hi = (_Float16)f;
          _Float16 lo = (_Float16)((f - (float)hi) * LO_SCALE);
          hv[j] = hi; lv[j] = lo;
        }
        jh[nt][c] = hv; jl[nt][c] = lv;
      }
  }

  const int nl = tid & 31;               // this thread's local neuron (same for all 4 b's)
  const int n_glob = wg*NS + nl;
  const float w_in_v = W_in[n_glob];

  #pragma unroll
  for (int c = 0; c < 4; ++c) {
    int e = tid + 256*c;
    sh_h[e] = 0.0f; sh_u[e] = U_CONST_; sh_x[e] = 1.0f;
  }
  if (tid < 32) sh_hI[tid] = 0.0f;
  __syncthreads();

  for (int t = 0; t < T_; ++t) {
    const int pb = t & 1;
    _Float16* vh = g_vh + (size_t)pb*(B_*N_);
    _Float16* vl = g_vl + (size_t)pb*(B_*N_);
    float* rp = g_rp + pb*(NWG*B_);

    // ---- phase A: R, v (split fp16), u/x update, partial R-sum (pre-barrier) ----
    #pragma unroll
    for (int c = 0; c < 4; ++c) {
      const int e = tid + 256*c;
      const int b = e >> 5;
      float h = sh_h[e], u = sh_u[e], x = sh_x[e];
      float R = rate_f(h);
      float v = u * x * R;
      _Float16 vhi = (_Float16)v;
      _Float16 vlo = (_Float16)((v - (float)vhi) * LO_SCALE);
      vh[b*N_ + n_glob] = vhi;
      vl[b*N_ + n_glob] = vlo;
      float du = (U_CONST_ - u)*(1.0f/TAU_F_) + U_CONST_*(1.0f - u)*R;
      float dx = (1.0f - x)*(1.0f/TAU_D_) - v;
      float u2 = u + du*DT_;
      float x2 = x + dx*DT_;
      sh_u[e] = u2; sh_x[e] = x2;
      out[U_OFF + (size_t)t*(B_*N_) + (size_t)b*N_ + n_glob] = u2;
      out[X_OFF + (size_t)t*(B_*N_) + (size_t)b*N_ + n_glob] = x2;
      // reduce R over the 32-lane half-wave sharing batch b
      float s = R;
      s += __shfl_xor(s, 1);  s += __shfl_xor(s, 2);  s += __shfl_xor(s, 4);
      s += __shfl_xor(s, 8);  s += __shfl_xor(s, 16);
      if ((lane & 31) == 0) sh_rsum[b] = s;
    }
    __syncthreads();
    if (tid < 32) {
      rp[wg*B_ + tid] = sh_rsum[tid];
      sh_inp[tid] = inp[t*B_ + tid];
    }

    // ---- device-wide barrier (manual grid.sync: 64 blocks are all co-resident) ----
    __syncthreads();                       // all waves' stores issued (vmcnt drained at s_barrier)
    if (tid == 0) {
      __threadfence();                     // agent-scope release: write back local L2 (cross-XCD)
      __hip_atomic_fetch_add(bar, 1u, __ATOMIC_RELAXED, __HIP_MEMORY_SCOPE_AGENT);
      const unsigned target = (unsigned)(t + 1) * NWG;
      while (__hip_atomic_load(bar, __ATOMIC_RELAXED, __HIP_MEMORY_SCOPE_AGENT) < target)
        __builtin_amdgcn_s_sleep(2);
      __threadfence();                     // agent-scope acquire: invalidate stale L1/L2 lines
    }
    __syncthreads();

    // ---- phase C: h_I update + split-fp16 MFMA over register-resident J ----
    if (tid < 32) {
      float s = 0.0f;
      #pragma unroll
      for (int g = 0; g < NWG; ++g) s += rp[g*B_ + tid];
      float hI = sh_hI[tid];
      sh_RI[tid] = rate_f(hI);                       // pre-update R_I
      float hI2 = hI + DT_*INV_TAU*(-hI + J_IE_*s);
      sh_hI[tid] = hI2;
      if (wg == 0) out[HI_OFF + (size_t)t*B_ + tid] = hI2;
    }
    {
      const int r = lane & 15, q = lane >> 4;
      f32x4 aH00 = {0,0,0,0}, aH01 = {0,0,0,0}, aH10 = {0,0,0,0}, aH11 = {0,0,0,0};
      f32x4 aL00 = {0,0,0,0}, aL01 = {0,0,0,0}, aL10 = {0,0,0,0}, aL11 = {0,0,0,0};
      const _Float16* vah = vh + (size_t)r*N_ + wave*512 + q*8;
      const _Float16* val = vl + (size_t)r*N_ + wave*512 + q*8;
      #pragma unroll
      for (int c = 0; c < 16; ++c) {
        half8 ah0 = *(const half8*)(vah + c*32);
        half8 ah1 = *(const half8*)(vah + 16*N_ + c*32);
        half8 al0 = *(const half8*)(val + c*32);
        half8 al1 = *(const half8*)(val + 16*N_ + c*32);
        // hi*hi
        aH00 = __builtin_amdgcn_mfma_f32_16x16x32_f16(ah0, jh[0][c], aH00, 0, 0, 0);
        aH01 = __builtin_amdgcn_mfma_f32_16x16x32_f16(ah0, jh[1][c], aH01, 0, 0, 0);
        aH10 = __builtin_amdgcn_mfma_f32_16x16x32_f16(ah1, jh[0][c], aH10, 0, 0, 0);
        aH11 = __builtin_amdgcn_mfma_f32_16x16x32_f16(ah1, jh[1][c], aH11, 0, 0, 0);
        // hi*lo + lo*hi (both pre-scaled by 2^12, folded back at the end)
        aL00 = __builtin_amdgcn_mfma_f32_16x16x32_f16(ah0, jl[0][c], aL00, 0, 0, 0);
        aL00 = __builtin_amdgcn_mfma_f32_16x16x32_f16(al0, jh[0][c], aL00, 0, 0, 0);
        aL01 = __builtin_amdgcn_mfma_f32_16x16x32_f16(ah0, jl[1][c], aL01, 0, 0, 0);
        aL01 = __builtin_amdgcn_mfma_f32_16x16x32_f16(al0, jh[1][c], aL01, 0, 0, 0);
        aL10 = __builtin_amdgcn_mfma_f32_16x16x32_f16(ah1, jl[0][c], aL10, 0, 0, 0);
        aL10 = __builtin_amdgcn_mfma_f32_16x16x32_f16(al1, jh[0][c], aL10, 0, 0, 0);
        aL11 = __builtin_amdgcn_mfma_f32_16x16x32_f16(ah1, jl[1][c], aL11, 0, 0, 0);
        aL11 = __builtin_amdgcn_mfma_f32_16x16x32_f16(al1, jh[1][c], aL11, 0, 0, 0);
      }
      #pragma unroll
      for (int i = 0; i < 4; ++i) {
        int row = q*4 + i;                            // C/D: col=lane&15, row=quad*4+reg
        sh_C[wave][ row     *32      + r] = aH00[i] + INV_LO_SCALE*aL00[i];
        sh_C[wave][ row     *32 + 16 + r] = aH01[i] + INV_LO_SCALE*aL01[i];
        sh_C[wave][(row+16) *32      + r] = aH10[i] + INV_LO_SCALE*aL10[i];
        sh_C[wave][(row+16) *32 + 16 + r] = aH11[i] + INV_LO_SCALE*aL11[i];
      }
    }
    __syncthreads();

    // ---- phase D: h update + all_h store ----
    #pragma unroll
    for (int c = 0; c < 4; ++c) {
      const int e = tid + 256*c;
      const int b = e >> 5;
      float syn = sh_C[0][e] + sh_C[1][e] + sh_C[2][e] + sh_C[3][e];
      float h = sh_h[e];
      float Ie = sh_inp[b] * w_in_v;
      float dh = (-h + syn + I_B_ + Ie)*INV_TAU - J_EI_*INV_TAU*sh_RI[b];
      float h2 = h + dh*DT_;
      sh_h[e] = h2;
      out[(size_t)t*(B_*N_) + (size_t)b*N_ + n_glob] = h2;
    }
    // no extra barrier needed before A(t+1): each thread re-reads only its own
    // sh_h elements; shared buffers are re-written only after the next barriers
  }
}

// outputs[t,b] = sum_n rate(all_h[t,b,n]) * W_out[n] — done post-hoc, no atomics
__global__ __launch_bounds__(256) void out_kernel(
    const float* __restrict__ allh, const float* __restrict__ W_out,
    float* __restrict__ outp)
{
  const int bid = blockIdx.x;              // t*32 + b
  const int tid = threadIdx.x;
  __shared__ float red[4];
  const float* hrow = allh + (size_t)bid * N_;
  float s = 0.0f;
  #pragma unroll
  for (int i = 0; i < 8; ++i) {
    int n = tid + 256*i;
    s += rate_f(hrow[n]) * W_out[n];
  }
  s += __shfl_xor(s, 32); s += __shfl_xor(s, 16); s += __shfl_xor(s, 8);
  s += __shfl_xor(s, 4);  s += __shfl_xor(s, 2);  s += __shfl_xor(s, 1);
  if ((tid & 63) == 0) red[tid >> 6] = s;
  __syncthreads();
  if (tid == 0) outp[bid] = red[0] + red[1] + red[2] + red[3];
}

extern "C" void kernel_launch(void* const* d_in, const int* in_sizes, int n_in,
                              void* d_out, int out_size, void* d_ws, size_t ws_size,
                              hipStream_t stream)
{
  const float* inp   = (const float*)d_in[0];
  const float* W_in  = (const float*)d_in[1];
  const float* J     = (const float*)d_in[2];
  const float* W_out = (const float*)d_in[3];
  float* out = (float*)d_out;
  unsigned* bar = (unsigned*)d_ws;      // 4-byte barrier counter (d_ws is poisoned -> must init)

  hipLaunchKernelGGL(init_kernel, dim3(1), dim3(64), 0, stream, bar);
  hipLaunchKernelGGL(stp_kernel, dim3(NWG), dim3(256), 0, stream,
                     inp, W_in, J, out, bar);
  hipLaunchKernelGGL(out_kernel, dim3(T_*B_), dim3(256), 0, stream,
                     out, W_out, out + OUT_OFF);
}

// Round 4
// 10257.260 us; speedup vs baseline: 1.7846x; 1.7846x over previous
//
#include <hip/hip_runtime.h>

#define N_ 2048
#define T_ 512
#define B_ 32
#define NWG 64            // 64 blocks, 1 per CU -> always co-resident (256 CUs)
#define NS 32
#define DT_ 1e-4f
#define U_CONST_ 0.3f
#define TAU_F_ 1.5f
#define TAU_D_ 0.3f
#define ALPHA_ 1.5f
#define I_B_ 8.0f
#define J_EI_ 1.1f
#define J_IE_ 2.2f
#define INV_TAU 125.0f          // 1/0.008
#define INV_ALPHA (1.0f/1.5f)
#define LO_SCALE 4096.0f        // 2^12: keeps lo parts out of fp16 denormal range
#define INV_LO_SCALE 2.44140625e-4f

// d_out float offsets: all_h, all_u, all_x, all_hI, outputs
#define U_OFF  (512ull*32*2048)
#define X_OFF  (2ull*512*32*2048)
#define HI_OFF (3ull*512*32*2048)
#define OUT_OFF (HI_OFF + 512ull*32)

typedef _Float16 half8 __attribute__((ext_vector_type(8)));
typedef float f32x4 __attribute__((ext_vector_type(4)));
typedef unsigned long long u64;
typedef u64 u64x2 __attribute__((ext_vector_type(2)));

// Cross-WG shared state. Accessed ONLY with system-scope relaxed atomics
// (sc0 sc1 -> L1/L2 bypass, coherent at the MALL). Written before read every
// step, so stale contents across launches are harmless.
__device__ u64   g_vh[2][(B_*N_)/4];    // v hi-halves, [b][n] packed 4 per qword
__device__ u64   g_vl[2][(B_*N_)/4];    // v lo-halves (pre-scaled by 2^12)
__device__ float g_rp[2][B_*NWG];       // R partial sums, [b][wg]
__device__ unsigned g_flags[NWG*16];    // per-WG epoch flag, 64B apart

#define SYS_LD_U64(p)   __hip_atomic_load((p), __ATOMIC_RELAXED, __HIP_MEMORY_SCOPE_SYSTEM)
#define SYS_LD_F32(p)   __hip_atomic_load((p), __ATOMIC_RELAXED, __HIP_MEMORY_SCOPE_SYSTEM)
#define SYS_LD_U32(p)   __hip_atomic_load((p), __ATOMIC_RELAXED, __HIP_MEMORY_SCOPE_SYSTEM)
#define SYS_ST_U32(p,v) __hip_atomic_store((p), (v), __ATOMIC_RELAXED, __HIP_MEMORY_SCOPE_SYSTEM)
#define SYS_ST_F32(p,v) __hip_atomic_store((p), (v), __ATOMIC_RELAXED, __HIP_MEMORY_SCOPE_SYSTEM)

__device__ inline float rate_f(float h) {
  float z = h * INV_ALPHA;
  return ALPHA_ * (fmaxf(z, 0.0f) + log1pf(expf(-fabsf(z))));
}

__device__ inline unsigned packpair(float a, float b, float scale_into_lo, bool lo_plane) {
  // helper not used; kept minimal below instead
  return 0;
}

// flags are monotonic within a launch; must start at 0 each launch
__global__ void init_kernel() {
  g_flags[threadIdx.x] = 0u;      // 1024 threads == NWG*16 entries
}

__global__ __launch_bounds__(256, 1) void stp_kernel(
    const float* __restrict__ inp, const float* __restrict__ W_in,
    const float* __restrict__ J, float* __restrict__ out)
{
  const int tid  = threadIdx.x;
  const int wg   = blockIdx.x;
  const int wave = tid >> 6;
  const int lane = tid & 63;

  __shared__ float sh_C[4][1024];
  __shared__ float sh_part[256];         // [gc(8)][b(32)]
  __shared__ float sh_hI[32], sh_RI[32], sh_inp[32];

  // ---- J slice -> registers as split fp16 B-fragments (unchanged from r3) ----
  half8 jh[2][16], jl[2][16];
  {
    const int r = lane & 15, q = lane >> 4;
    #pragma unroll
    for (int nt = 0; nt < 2; ++nt)
      #pragma unroll
      for (int c = 0; c < 16; ++c) {
        const float* src = J + (size_t)(wg*NS + nt*16 + r) * N_ + wave*512 + c*32 + q*8;
        half8 hv, lv;
        #pragma unroll
        for (int j = 0; j < 8; ++j) {
          float f = src[j];
          _Float16 hi = (_Float16)f;
          _Float16 lo = (_Float16)((f - (float)hi) * LO_SCALE);
          hv[j] = hi; lv[j] = lo;
        }
        jh[nt][c] = hv; jl[nt][c] = lv;
      }
  }

  // thread -> (2 adjacent neurons) x (2 batches); state lives in registers
  const int np = tid & 15;               // neuron-pair index within WG
  const int n0 = wg*NS + 2*np;           // global neuron (even)
  const int bq = tid >> 4;               // batch 0..15 (+16 for c=1)
  const float w0 = W_in[n0], w1 = W_in[n0+1];

  float hh[2][2], uu[2][2], xx[2][2];
  #pragma unroll
  for (int c = 0; c < 2; ++c)
    #pragma unroll
    for (int j = 0; j < 2; ++j) { hh[c][j] = 0.0f; uu[c][j] = U_CONST_; xx[c][j] = 1.0f; }

  if (tid < 32) sh_hI[tid] = 0.0f;
  __syncthreads();

  for (int t = 0; t < T_; ++t) {
    const int pb = t & 1;
    unsigned* vhd = (unsigned*)g_vh[pb];
    unsigned* vld = (unsigned*)g_vl[pb];

    // ---- phase A: R, v (split fp16, system-store), u/x reg update, R-partials ----
    #pragma unroll
    for (int c = 0; c < 2; ++c) {
      const int b = bq + 16*c;
      float R0 = rate_f(hh[c][0]), R1 = rate_f(hh[c][1]);
      float v0 = uu[c][0]*xx[c][0]*R0, v1 = uu[c][1]*xx[c][1]*R1;
      _Float16 h0 = (_Float16)v0, h1 = (_Float16)v1;
      _Float16 l0 = (_Float16)((v0 - (float)h0) * LO_SCALE);
      _Float16 l1 = (_Float16)((v1 - (float)h1) * LO_SCALE);
      unsigned hp = (unsigned)__builtin_bit_cast(unsigned short, h0)
                  | ((unsigned)__builtin_bit_cast(unsigned short, h1) << 16);
      unsigned lp = (unsigned)__builtin_bit_cast(unsigned short, l0)
                  | ((unsigned)__builtin_bit_cast(unsigned short, l1) << 16);
      const unsigned idx = (unsigned)(b*N_ + n0) >> 1;
      SYS_ST_U32(vhd + idx, hp);
      SYS_ST_U32(vld + idx, lp);
      uu[c][0] += ((U_CONST_-uu[c][0])*(1.0f/TAU_F_) + U_CONST_*(1.0f-uu[c][0])*R0)*DT_;
      uu[c][1] += ((U_CONST_-uu[c][1])*(1.0f/TAU_F_) + U_CONST_*(1.0f-uu[c][1])*R1)*DT_;
      xx[c][0] += ((1.0f-xx[c][0])*(1.0f/TAU_D_) - v0)*DT_;
      xx[c][1] += ((1.0f-xx[c][1])*(1.0f/TAU_D_) - v1)*DT_;
      // WG-complete R sum for batch b lives in this 16-lane group
      float s = R0 + R1;
      s += __shfl_xor(s, 1); s += __shfl_xor(s, 2);
      s += __shfl_xor(s, 4); s += __shfl_xor(s, 8);
      if ((lane & 15) == 0) SYS_ST_F32(&g_rp[pb][b*NWG + wg], s);
    }

    // ---- device barrier: arrive ----
    __syncthreads();                         // per-wave vmcnt(0) before s_barrier:
                                             // all bypass-stores are at the MALL
    if (tid == 0) SYS_ST_U32(&g_flags[wg*16], (unsigned)(t + 1));

    // overlapped with barrier wait: output stores + inp load
    #pragma unroll
    for (int c = 0; c < 2; ++c) {
      const int b = bq + 16*c;
      const size_t o = (size_t)t*(B_*N_) + (size_t)b*N_ + n0;
      *(float2*)&out[U_OFF + o] = make_float2(uu[c][0], uu[c][1]);
      *(float2*)&out[X_OFF + o] = make_float2(xx[c][0], xx[c][1]);
    }
    if (tid < 32) sh_inp[tid] = inp[t*B_ + tid];

    // ---- device barrier: wait (wave0 polls 64 flags, one per lane) ----
    if (wave == 0) {
      const unsigned target = (unsigned)(t + 1);
      while (true) {
        unsigned f = SYS_LD_U32(&g_flags[lane*16]);
        if (__ballot(f >= target) == ~0ull) break;
        __builtin_amdgcn_s_sleep(1);
      }
    }
    __syncthreads();
    __atomic_signal_fence(__ATOMIC_ACQUIRE);

    // ---- R-partial gather (parallel, overlaps MFMA scheduling) ----
    {
      const int b2 = tid & 31, gc = tid >> 5;
      float s = 0.0f;
      #pragma unroll
      for (int k = 0; k < 8; ++k)
        s += SYS_LD_F32(&g_rp[pb][b2*NWG + gc*8 + k]);
      sh_part[gc*32 + b2] = s;
    }

    // ---- phase C: split-fp16 MFMA over register-resident J ----
    {
      const int r = lane & 15, q = lane >> 4;
      f32x4 aH00 = {0,0,0,0}, aH01 = {0,0,0,0}, aH10 = {0,0,0,0}, aH11 = {0,0,0,0};
      f32x4 aL00 = {0,0,0,0}, aL01 = {0,0,0,0}, aL10 = {0,0,0,0}, aL11 = {0,0,0,0};
      const int base0 = (r*N_      + wave*512 + q*8) >> 2;   // qword index
      const int base1 = ((r+16)*N_ + wave*512 + q*8) >> 2;
      #pragma unroll
      for (int c = 0; c < 16; ++c) {
        const int o0 = base0 + c*8, o1 = base1 + c*8;
        u64x2 th0 = { SYS_LD_U64(&g_vh[pb][o0]), SYS_LD_U64(&g_vh[pb][o0+1]) };
        u64x2 tl0 = { SYS_LD_U64(&g_vl[pb][o0]), SYS_LD_U64(&g_vl[pb][o0+1]) };
        u64x2 th1 = { SYS_LD_U64(&g_vh[pb][o1]), SYS_LD_U64(&g_vh[pb][o1+1]) };
        u64x2 tl1 = { SYS_LD_U64(&g_vl[pb][o1]), SYS_LD_U64(&g_vl[pb][o1+1]) };
        half8 ah0 = __builtin_bit_cast(half8, th0);
        half8 al0 = __builtin_bit_cast(half8, tl0);
        half8 ah1 = __builtin_bit_cast(half8, th1);
        half8 al1 = __builtin_bit_cast(half8, tl1);
        aH00 = __builtin_amdgcn_mfma_f32_16x16x32_f16(ah0, jh[0][c], aH00, 0, 0, 0);
        aH01 = __builtin_amdgcn_mfma_f32_16x16x32_f16(ah0, jh[1][c], aH01, 0, 0, 0);
        aH10 = __builtin_amdgcn_mfma_f32_16x16x32_f16(ah1, jh[0][c], aH10, 0, 0, 0);
        aH11 = __builtin_amdgcn_mfma_f32_16x16x32_f16(ah1, jh[1][c], aH11, 0, 0, 0);
        aL00 = __builtin_amdgcn_mfma_f32_16x16x32_f16(ah0, jl[0][c], aL00, 0, 0, 0);
        aL00 = __builtin_amdgcn_mfma_f32_16x16x32_f16(al0, jh[0][c], aL00, 0, 0, 0);
        aL01 = __builtin_amdgcn_mfma_f32_16x16x32_f16(ah0, jl[1][c], aL01, 0, 0, 0);
        aL01 = __builtin_amdgcn_mfma_f32_16x16x32_f16(al0, jh[1][c], aL01, 0, 0, 0);
        aL10 = __builtin_amdgcn_mfma_f32_16x16x32_f16(ah1, jl[0][c], aL10, 0, 0, 0);
        aL10 = __builtin_amdgcn_mfma_f32_16x16x32_f16(al1, jh[0][c], aL10, 0, 0, 0);
        aL11 = __builtin_amdgcn_mfma_f32_16x16x32_f16(ah1, jl[1][c], aL11, 0, 0, 0);
        aL11 = __builtin_amdgcn_mfma_f32_16x16x32_f16(al1, jh[1][c], aL11, 0, 0, 0);
      }
      #pragma unroll
      for (int i = 0; i < 4; ++i) {
        int row = q*4 + i;                   // C/D: col=lane&15, row=quad*4+reg
        sh_C[wave][ row     *32      + r] = aH00[i] + INV_LO_SCALE*aL00[i];
        sh_C[wave][ row     *32 + 16 + r] = aH01[i] + INV_LO_SCALE*aL01[i];
        sh_C[wave][(row+16) *32      + r] = aH10[i] + INV_LO_SCALE*aL10[i];
        sh_C[wave][(row+16) *32 + 16 + r] = aH11[i] + INV_LO_SCALE*aL11[i];
      }
    }
    __syncthreads();

    // ---- h_I update (needs sh_part complete) ----
    if (tid < 32) {
      float s = 0.0f;
      #pragma unroll
      for (int gc = 0; gc < 8; ++gc) s += sh_part[gc*32 + tid];
      float hI = sh_hI[tid];
      sh_RI[tid] = rate_f(hI);               // pre-update R_I
      float hI2 = hI + DT_*INV_TAU*(-hI + J_IE_*s);
      sh_hI[tid] = hI2;
      if (wg == 0) out[HI_OFF + (size_t)t*B_ + tid] = hI2;
    }
    __syncthreads();

    // ---- phase D: h update (registers) + all_h store ----
    #pragma unroll
    for (int c = 0; c < 2; ++c) {
      const int b = bq + 16*c;
      const int e = b*32 + 2*np;
      float sy0 = sh_C[0][e]   + sh_C[1][e]   + sh_C[2][e]   + sh_C[3][e];
      float sy1 = sh_C[0][e+1] + sh_C[1][e+1] + sh_C[2][e+1] + sh_C[3][e+1];
      float ib = sh_inp[b];
      float ri = J_EI_*INV_TAU*sh_RI[b];
      float dh0 = (-hh[c][0] + sy0 + I_B_ + ib*w0)*INV_TAU - ri;
      float dh1 = (-hh[c][1] + sy1 + I_B_ + ib*w1)*INV_TAU - ri;
      hh[c][0] += dh0*DT_;
      hh[c][1] += dh1*DT_;
      *(float2*)&out[(size_t)t*(B_*N_) + (size_t)b*N_ + n0] = make_float2(hh[c][0], hh[c][1]);
    }
    // next A reads only this thread's registers; shared buffers are re-written
    // only after the next barriers -> no extra __syncthreads needed here
  }
}

// outputs[t,b] = sum_n rate(all_h[t,b,n]) * W_out[n] — post-hoc, no atomics
__global__ __launch_bounds__(256) void out_kernel(
    const float* __restrict__ allh, const float* __restrict__ W_out,
    float* __restrict__ outp)
{
  const int bid = blockIdx.x;              // t*32 + b
  const int tid = threadIdx.x;
  __shared__ float red[4];
  const float* hrow = allh + (size_t)bid * N_;
  float s = 0.0f;
  #pragma unroll
  for (int i = 0; i < 8; ++i) {
    int n = tid + 256*i;
    s += rate_f(hrow[n]) * W_out[n];
  }
  s += __shfl_xor(s, 32); s += __shfl_xor(s, 16); s += __shfl_xor(s, 8);
  s += __shfl_xor(s, 4);  s += __shfl_xor(s, 2);  s += __shfl_xor(s, 1);
  if ((tid & 63) == 0) red[tid >> 6] = s;
  __syncthreads();
  if (tid == 0) outp[bid] = red[0] + red[1] + red[2] + red[3];
}

extern "C" void kernel_launch(void* const* d_in, const int* in_sizes, int n_in,
                              void* d_out, int out_size, void* d_ws, size_t ws_size,
                              hipStream_t stream)
{
  const float* inp   = (const float*)d_in[0];
  const float* W_in  = (const float*)d_in[1];
  const float* J     = (const float*)d_in[2];
  const float* W_out = (const float*)d_in[3];
  float* out = (float*)d_out;

  hipLaunchKernelGGL(init_kernel, dim3(1), dim3(NWG*16), 0, stream);
  hipLaunchKernelGGL(stp_kernel, dim3(NWG), dim3(256), 0, stream,
                     inp, W_in, J, out);
  hipLaunchKernelGGL(out_kernel, dim3(T_*B_), dim3(256), 0, stream,
                     out, W_out, out + OUT_OFF);
}